// Round 11
// baseline (137.588 us; speedup 1.0000x reference)
//
#include <hip/hip_runtime.h>

typedef short v8s __attribute__((ext_vector_type(8)));
typedef float v4f __attribute__((ext_vector_type(4)));

#define LOG2E 1.44269504088896340736f

// ---- d_ws layout (bytes) ----
#define WS_FBF_T 0u          // u16 [8][4096][64]  f transposed (n-major, MFMA rows)
#define WS_FVP   4194304u    // u16 [8][64][4096]  f c-major, per-32 key-permuted cols
#define WS_G     8388608u    // f32 [8][4096]      row squared-norms
#define WS_BMAX  8519680u    // f32 [8][64]        per-chunk partial max of g
#define WS_NEED  8521728u

__device__ __forceinline__ unsigned short f2bf_rne(float f) {
  unsigned int u = __builtin_bit_cast(unsigned int, f);
  u += 0x7FFFu + ((u >> 16) & 1u);
  return (unsigned short)(u >> 16);
}

__device__ __forceinline__ unsigned int pack_hi16(float hi, float lo) {
#if defined(__has_builtin) && __has_builtin(__builtin_amdgcn_perm)
  return __builtin_amdgcn_perm(__builtin_bit_cast(unsigned int, hi),
                               __builtin_bit_cast(unsigned int, lo), 0x07060302u);
#else
  return (__builtin_bit_cast(unsigned int, hi) & 0xFFFF0000u) |
         (__builtin_bit_cast(unsigned int, lo) >> 16);
#endif
}

// async global->LDS, 16 B per lane; LDS dest = wave-uniform base + lane*16
__device__ __forceinline__ void cp16(const void* gsrc, void* ldst) {
  __builtin_amdgcn_global_load_lds(
      (const __attribute__((address_space(1))) unsigned int*)gsrc,
      (__attribute__((address_space(3))) unsigned int*)ldst, 16, 0, 0);
}

// ============ pre-pass (R7 form, proven) ============
__global__ __launch_bounds__(256) void prep_kernel(
    const float* __restrict__ x, unsigned short* __restrict__ fbf_t,
    unsigned short* __restrict__ fvp, float* __restrict__ g, float* __restrict__ bmax) {
  __shared__ float red[4][64];
  const int t = threadIdx.x;
  const int b = blockIdx.x & 7, ch = blockIdx.x >> 3;
  const int n0 = ch << 6, nn = t & 63, n = n0 + nn, cg = t >> 6;

  const int kin = nn & 31;
  const int slot = (kin < 16) ? (((kin >> 2) << 3) + (kin & 3))
                              : ((((kin - 16) >> 2) << 3) + ((kin - 16) & 3) + 4);
  const int ncol = (n & ~31) + slot;

  float sq = 0.f;
  unsigned short w[16];
#pragma unroll
  for (int j = 0; j < 16; ++j) {
    const int c = cg * 16 + j;
    float v = x[((size_t)(b * 64 + c) << 12) + n];
    sq = __builtin_fmaf(v, v, sq);
    w[j] = f2bf_rne(v);
  }
  unsigned short* ft = fbf_t + ((size_t)b << 18) + (size_t)n * 64 + cg * 16;
  *(v8s*)ft = *(v8s*)&w[0];
  *(v8s*)(ft + 8) = *(v8s*)&w[8];
#pragma unroll
  for (int j = 0; j < 16; ++j)
    fvp[((size_t)(b * 64 + cg * 16 + j) << 12) + ncol] = w[j];

  red[cg][nn] = sq;
  __syncthreads();
  if (t < 64) {
    float tot = (red[0][t] + red[1][t]) + (red[2][t] + red[3][t]);
    g[b * 4096 + n0 + t] = tot;
    float m = tot;
    m = fmaxf(m, __shfl_xor(m, 1, 64));
    m = fmaxf(m, __shfl_xor(m, 2, 64));
    m = fmaxf(m, __shfl_xor(m, 4, 64));
    m = fmaxf(m, __shfl_xor(m, 8, 64));
    m = fmaxf(m, __shfl_xor(m, 16, 64));
    m = fmaxf(m, __shfl_xor(m, 32, 64));
    if (t == 0) bmax[b * 64 + ch] = m;
  }
}

// ============ main: jq=8 / KTILE=256 / async global_load_lds staging ============
// grid 256 = 8 b (&7: round-robin XCD-aligned, R10-verified) x 32 q-tiles of 128.
// 512 thr = 8 waves, wave w owns keys [w*32, w*32+32) of each 256-key tile.
// LDS dbuf: buf p at p*65536: K[256 rows][128 B, chunk-rotated by row&7],
//                             V[64 rows][512 B, chunk-rotated by row&31] @+32768.
// Swizzles give pad-free (DMA-compatible) layouts with <=2-way bank aliasing.
__global__ __launch_bounds__(512, 2) void chanattn_main(
    const float* __restrict__ x, const unsigned short* __restrict__ fbf_t,
    const unsigned short* __restrict__ fvp, const float* __restrict__ g,
    const float* __restrict__ bmax, float* __restrict__ out) {
  __shared__ __align__(16) unsigned char smem[135168];  // 2*65536 + lred 4096
  float* lred = (float*)(smem + 131072);                // f32[128][8]
  const int BUFB = 65536;

  const int tid = threadIdx.x;
  const int wave = tid >> 6, lane = tid & 63, quad = lane >> 4, l15 = lane & 15;
  const int b = blockIdx.x & 7, qt = blockIdx.x >> 3;

  const unsigned short* fT = fbf_t + ((size_t)b << 18);  // [n][c]
  const unsigned short* fV = fvp + ((size_t)b << 18);    // [c][n'] permuted
  const unsigned char* fTb = (const unsigned char*)fT;
  const unsigned char* fVb = (const unsigned char*)fV;

  const int lrow8 = lane >> 3, ls8 = lane & 7;    // K DMA lane decomposition
  const int lrow2 = lane >> 5;                    // V DMA
  const int ls32 = lane & 31;

  // ---- issue DMA for a tile into buffer p ----
  auto issue = [&](int kt, int p) {
    const int k0 = kt << 8;
#pragma unroll
    for (int i = 0; i < 4; ++i) {   // K: 4 x 1024 B per wave
      int row = (wave * 4 + i) * 8 + lrow8;        // key row 0..255
      int c = (ls8 + row) & 7;                     // global 16B chunk (swizzle inverse)
      cp16(fTb + ((size_t)(k0 + row) << 7) + (c << 4),
           smem + p * BUFB + (wave * 4 + i) * 1024 + lane * 16);
    }
#pragma unroll
    for (int i = 0; i < 4; ++i) {   // V: 4 x 1024 B per wave
      int row = (wave * 4 + i) * 2 + lrow2;        // channel row 0..63
      int c = (ls32 + row) & 31;                   // 16B chunk within 512B row
      cp16(fVb + ((size_t)row << 13) + (size_t)(k0 << 1) + (c << 4),
           smem + p * BUFB + 32768 + (wave * 4 + i) * 1024 + lane * 16);
    }
  };

  issue(0, 0);   // tile 0 DMA in flight under the prologue

  // ---- prologue: bQ straight from global (Q never touches LDS), msc ----
  v8s bQ[8][2];
#pragma unroll
  for (int jq = 0; jq < 8; ++jq)
#pragma unroll
    for (int cs = 0; cs < 2; ++cs)
      bQ[jq][cs] =
          *(const v8s*)&fT[(size_t)(qt * 128 + jq * 16 + l15) * 64 + cs * 32 + quad * 8];

  float gm = bmax[b * 64 + lane];
  gm = fmaxf(gm, __shfl_xor(gm, 1, 64));
  gm = fmaxf(gm, __shfl_xor(gm, 2, 64));
  gm = fmaxf(gm, __shfl_xor(gm, 4, 64));
  gm = fmaxf(gm, __shfl_xor(gm, 8, 64));
  gm = fmaxf(gm, __shfl_xor(gm, 16, 64));
  gm = fmaxf(gm, __shfl_xor(gm, 32, 64));
  float msc[8];
#pragma unroll
  for (int jq = 0; jq < 8; ++jq)
    msc[jq] =
        __builtin_sqrtf(g[b * 4096 + qt * 128 + jq * 16 + l15] * gm) * LOG2E;

  v4f oacc[8][4];   // [jq][ct] O^T partial: col=q(l15), row=c(quad*4+r)
  float rsum[8];
#pragma unroll
  for (int jq = 0; jq < 8; ++jq) {
    rsum[jq] = 0.f;
#pragma unroll
    for (int ct = 0; ct < 4; ++ct) oacc[jq][ct] = (v4f){0.f, 0.f, 0.f, 0.f};
  }

  for (int kt = 0; kt < 16; ++kt) {
    __syncthreads();   // own-wave vmcnt drain before barrier => tile kt DMA done
    const int p = kt & 1;
    if (kt + 1 < 16) issue(kt + 1, p ^ 1);   // buffer of kt-1: reads finished pre-barrier

    // ---- LDS frag reads (swizzled addresses; <=2-way bank aliasing) ----
    v8s aK[2][2];   // A[m=key][k=c]; m=l15 within 16-key tile t
#pragma unroll
    for (int t = 0; t < 2; ++t)
#pragma unroll
      for (int cs = 0; cs < 2; ++cs) {
        int row = wave * 32 + t * 16 + l15;
        int s = ((cs * 4 + quad) - row) & 7;
        aK[t][cs] = *(const v8s*)(smem + p * BUFB + row * 128 + s * 16);
      }
    v8s aV[4];      // A[m=c][k=key(permuted)]
#pragma unroll
    for (int ct = 0; ct < 4; ++ct) {
      int row = ct * 16 + l15;
      int s = ((wave * 4 + quad) - row) & 31;
      aV[ct] = *(const v8s*)(smem + p * BUFB + 32768 + row * 512 + s * 16);
    }

    // ---- 8 q-tiles: QK -> exp2/pack -> PV, all from registers ----
#pragma unroll
    for (int jq = 0; jq < 8; ++jq) {
      v4f s0 = (v4f){0.f, 0.f, 0.f, 0.f}, s1 = (v4f){0.f, 0.f, 0.f, 0.f};
#pragma unroll
      for (int cs = 0; cs < 2; ++cs) {
        s0 = __builtin_amdgcn_mfma_f32_16x16x32_bf16(aK[0][cs], bQ[jq][cs], s0, 0, 0, 0);
        s1 = __builtin_amdgcn_mfma_f32_16x16x32_bf16(aK[1][cs], bQ[jq][cs], s1, 0, 0, 0);
      }
      float p0[4], p1[4];
#pragma unroll
      for (int r = 0; r < 4; ++r) {
        p0[r] = __builtin_amdgcn_exp2f(__builtin_fmaf(s0[r], LOG2E, -msc[jq]));
        p1[r] = __builtin_amdgcn_exp2f(__builtin_fmaf(s1[r], LOG2E, -msc[jq]));
      }
      rsum[jq] += ((p0[0] + p0[1]) + (p0[2] + p0[3])) +
                  ((p1[0] + p1[1]) + (p1[2] + p1[3]));
      uint4 up;
      up.x = pack_hi16(p0[1], p0[0]);
      up.y = pack_hi16(p0[3], p0[2]);
      up.z = pack_hi16(p1[1], p1[0]);
      up.w = pack_hi16(p1[3], p1[2]);
      v8s bp = __builtin_bit_cast(v8s, up);
#pragma unroll
      for (int ct = 0; ct < 4; ++ct)
        oacc[jq][ct] =
            __builtin_amdgcn_mfma_f32_16x16x32_bf16(aV[ct], bp, oacc[jq][ct], 0, 0, 0);
    }
  }

  // ---- epilogue: fold l over quads, merge 8 kg waves, residual store ----
#pragma unroll
  for (int jq = 0; jq < 8; ++jq) {
    float s = rsum[jq];
    s += __shfl_xor(s, 16, 64);
    s += __shfl_xor(s, 32, 64);
    rsum[jq] = s;
  }
  __syncthreads();   // K-loop LDS reads done; lred region never aliases tiles anyway
  if (quad == 0) {
#pragma unroll
    for (int jq = 0; jq < 8; ++jq)
      lred[(jq * 16 + l15) * 8 + wave] = rsum[jq];
  }
  __syncthreads();
  float inv[8];
#pragma unroll
  for (int jq = 0; jq < 8; ++jq) {
    const float4 a = *(const float4*)&lred[(jq * 16 + l15) * 8];
    const float4 c = *(const float4*)&lred[(jq * 16 + l15) * 8 + 4];
    inv[jq] = __builtin_amdgcn_rcpf(((a.x + a.y) + (a.z + a.w)) +
                                    ((c.x + c.y) + (c.z + c.w)));
  }

  float* Obuf = (float*)smem;   // f32[64 c][132 q] overlay (33792 B, tiles dead)
#pragma unroll
  for (int round = 0; round < 8; ++round) {
    if (wave == round) {
#pragma unroll
      for (int jq = 0; jq < 8; ++jq)
#pragma unroll
        for (int ct = 0; ct < 4; ++ct)
#pragma unroll
          for (int r = 0; r < 4; ++r) {
            float val = oacc[jq][ct][r] * inv[jq];
            float* p = &Obuf[(ct * 16 + quad * 4 + r) * 132 + jq * 16 + l15];
            if (round == 0) *p = val; else *p += val;
          }
    }
    __syncthreads();
  }
#pragma unroll
  for (int j = 0; j < 4; ++j) {
    int idx = tid + j * 512;            // 0..2047 over (c, q4)
    int c = idx >> 5, q4 = idx & 31;
    const float4 o = *(const float4*)&Obuf[c * 132 + q4 * 4];
    size_t gidx = ((size_t)(b * 64 + c) << 12) + (unsigned)(qt * 128 + q4 * 4);
    const float4 xv = *(const float4*)(x + gidx);
    float4 rv;
    rv.x = xv.x + o.x; rv.y = xv.y + o.y; rv.z = xv.z + o.z; rv.w = xv.w + o.w;
    *(float4*)(out + gidx) = rv;
  }
}

// ============ fallback (R1 kernel, proven correct) if ws too small ============
__global__ __launch_bounds__(512) void
chanattn_fallback(const float* __restrict__ x, float* __restrict__ out) {
  __shared__ __align__(16) unsigned char smem[54272];
  unsigned short* sKt = (unsigned short*)smem;
  unsigned short* sVc = (unsigned short*)(smem + 18432);
  unsigned short* sP  = (unsigned short*)(smem + 35840);
  const int tid = threadIdx.x;
  const int wave = tid >> 6, lane = tid & 63, quad = lane >> 4, l15 = lane & 15;
  const int b = blockIdx.x & 7, qt = blockIdx.x >> 3;
  const float* fb = x + (size_t)b * (64 * 4096);
  const int skey = tid & 127, sc0 = (tid >> 7) << 4;
  {
    float vq[16];
#pragma unroll
    for (int j = 0; j < 16; ++j) vq[j] = fb[(sc0 + j) * 4096 + qt * 128 + skey];
    unsigned short us[16];
#pragma unroll
    for (int j = 0; j < 16; ++j) us[j] = f2bf_rne(vq[j]);
#pragma unroll
    for (int h = 0; h < 2; ++h) {
      v8s t;
#pragma unroll
      for (int j = 0; j < 8; ++j) t[j] = (short)us[h * 8 + j];
      *(v8s*)&sKt[skey * 72 + sc0 + h * 8] = t;
    }
  }
  float vk[16];
#pragma unroll
  for (int j = 0; j < 16; ++j) vk[j] = fb[(sc0 + j) * 4096 + skey];
  __syncthreads();
  v8s aq[2];
#pragma unroll
  for (int cs = 0; cs < 2; ++cs)
    aq[cs] = *(const v8s*)&sKt[(wave * 16 + l15) * 72 + cs * 32 + quad * 8];
  __syncthreads();
  v4f oacc[4];
#pragma unroll
  for (int ct = 0; ct < 4; ++ct) oacc[ct] = (v4f){0.f, 0.f, 0.f, 0.f};
  float m_run[4], l_run[4];
#pragma unroll
  for (int r = 0; r < 4; ++r) { m_run[r] = -3.0e38f; l_run[r] = 0.f; }
  unsigned short* sPw = sP + wave * (16 * 72);
  for (int kt = 0; kt < 32; ++kt) {
    {
      unsigned short us[16];
#pragma unroll
      for (int j = 0; j < 16; ++j) us[j] = f2bf_rne(vk[j]);
#pragma unroll
      for (int h = 0; h < 2; ++h) {
        v8s t;
#pragma unroll
        for (int j = 0; j < 8; ++j) t[j] = (short)us[h * 8 + j];
        *(v8s*)&sKt[skey * 72 + sc0 + h * 8] = t;
      }
#pragma unroll
      for (int j = 0; j < 16; ++j) sVc[(sc0 + j) * 136 + skey] = us[j];
    }
    __syncthreads();
    if (kt + 1 < 32) {
      const int m0 = (kt + 1) * 128;
#pragma unroll
      for (int j = 0; j < 16; ++j) vk[j] = fb[(sc0 + j) * 4096 + m0 + skey];
    }
    v4f sacc[8];
#pragma unroll
    for (int t = 0; t < 8; ++t) {
      v4f acc = (v4f){0.f, 0.f, 0.f, 0.f};
#pragma unroll
      for (int cs = 0; cs < 2; ++cs) {
        v8s bf = *(const v8s*)&sKt[(t * 16 + l15) * 72 + cs * 32 + quad * 8];
        acc = __builtin_amdgcn_mfma_f32_16x16x32_bf16(aq[cs], bf, acc, 0, 0, 0);
      }
      sacc[t] = acc;
    }
    float alpha[4], msc[4], rsum[4];
#pragma unroll
    for (int r = 0; r < 4; ++r) {
      float mv = sacc[0][r];
#pragma unroll
      for (int t = 1; t < 8; ++t) mv = fmaxf(mv, sacc[t][r]);
      mv = fmaxf(mv, __shfl_xor(mv, 8, 64));
      mv = fmaxf(mv, __shfl_xor(mv, 4, 64));
      mv = fmaxf(mv, __shfl_xor(mv, 2, 64));
      mv = fmaxf(mv, __shfl_xor(mv, 1, 64));
      float mnew = fmaxf(m_run[r], mv);
      alpha[r] = __builtin_amdgcn_exp2f((m_run[r] - mnew) * LOG2E);
      m_run[r] = mnew;
      msc[r] = mnew * LOG2E;
      l_run[r] *= alpha[r];
      rsum[r] = 0.f;
    }
#pragma unroll
    for (int ct = 0; ct < 4; ++ct)
#pragma unroll
      for (int r = 0; r < 4; ++r) oacc[ct][r] *= alpha[r];
#pragma unroll
    for (int half = 0; half < 2; ++half) {
#pragma unroll
      for (int t = half * 4; t < half * 4 + 4; ++t)
#pragma unroll
        for (int r = 0; r < 4; ++r) {
          float p = __builtin_amdgcn_exp2f(__builtin_fmaf(sacc[t][r], LOG2E, -msc[r]));
          rsum[r] += p;
          sPw[(quad * 4 + r) * 72 + (t - half * 4) * 16 + l15] = f2bf_rne(p);
        }
      asm volatile("s_waitcnt lgkmcnt(0)" ::: "memory");
#pragma unroll
      for (int ms = 0; ms < 2; ++ms) {
        v8s af = *(const v8s*)&sPw[l15 * 72 + ms * 32 + quad * 8];
#pragma unroll
        for (int ct = 0; ct < 4; ++ct) {
          v8s bf = *(const v8s*)&sVc[(ct * 16 + l15) * 136 + (half * 2 + ms) * 32 + quad * 8];
          oacc[ct] = __builtin_amdgcn_mfma_f32_16x16x32_bf16(af, bf, oacc[ct], 0, 0, 0);
        }
      }
      asm volatile("s_waitcnt lgkmcnt(0)" ::: "memory");
    }
#pragma unroll
    for (int r = 0; r < 4; ++r) {
      float s = rsum[r];
      s += __shfl_xor(s, 8, 64);
      s += __shfl_xor(s, 4, 64);
      s += __shfl_xor(s, 2, 64);
      s += __shfl_xor(s, 1, 64);
      l_run[r] += s;
    }
    __syncthreads();
  }
  float inv[4];
#pragma unroll
  for (int r = 0; r < 4; ++r) inv[r] = __builtin_amdgcn_rcpf(l_run[r]);
  float* sOt = (float*)smem;
#pragma unroll
  for (int ct = 0; ct < 4; ++ct)
#pragma unroll
    for (int r = 0; r < 4; ++r)
      sOt[(ct * 16 + l15) * 132 + wave * 16 + quad * 4 + r] = oacc[ct][r] * inv[r];
  __syncthreads();
#pragma unroll
  for (int j = 0; j < 4; ++j) {
    int idx = tid + j * 512;
    int nv = idx & 31, c = idx >> 5;
    float4 o = *(const float4*)&sOt[c * 132 + nv * 4];
    size_t gaddr = (size_t)b * (64 * 4096) + (size_t)c * 4096 + (size_t)(qt * 128 + nv * 4);
    float4 xv = *(const float4*)(x + gaddr);
    float4 res = make_float4(xv.x + o.x, xv.y + o.y, xv.z + o.z, xv.w + o.w);
    *(float4*)(out + gaddr) = res;
  }
}

extern "C" void kernel_launch(void* const* d_in, const int* in_sizes, int n_in,
                              void* d_out, int out_size, void* d_ws, size_t ws_size,
                              hipStream_t stream) {
  const float* xin = (const float*)d_in[0];
  float* out = (float*)d_out;
  if (ws_size >= (size_t)WS_NEED) {
    unsigned short* fbf_t = (unsigned short*)((char*)d_ws + WS_FBF_T);
    unsigned short* fvp = (unsigned short*)((char*)d_ws + WS_FVP);
    float* g = (float*)((char*)d_ws + WS_G);
    float* bmax = (float*)((char*)d_ws + WS_BMAX);
    prep_kernel<<<dim3(512), dim3(256), 0, stream>>>(xin, fbf_t, fvp, g, bmax);
    chanattn_main<<<dim3(256), dim3(512), 0, stream>>>(xin, fbf_t, fvp, g, bmax, out);
  } else {
    chanattn_fallback<<<dim3(256), dim3(512), 0, stream>>>(xin, out);
  }
}